// Round 2
// baseline (420.999 us; speedup 1.0000x reference)
//
#include <hip/hip_runtime.h>

// out = (x^2) * 0.1, fp32 elementwise. N = 64*1024*1024 = 67108864.
// Memory-bound. x (268 MB) nearly fits the 256 MB Infinity Cache; out is
// write-once. Strategy: temporal loads for x (L3 reuse across graph replays),
// non-temporal stores for out (nt flag -> don't evict x from L3).

typedef float vfloat4 __attribute__((ext_vector_type(4)));

__global__ void poly_sq_scale_v4(const vfloat4* __restrict__ x,
                                 vfloat4* __restrict__ out,
                                 int n4) {
    int i = blockIdx.x * blockDim.x + threadIdx.x;
    if (i < n4) {
        vfloat4 v = x[i];           // temporal: let L3 keep x
        vfloat4 r = v * v * 0.1f;
        __builtin_nontemporal_store(r, &out[i]);  // nt: bypass cache priority
    }
}

// Tail handler (N % 4 == 0 here, kept for safety).
__global__ void poly_sq_scale_tail(const float* __restrict__ x,
                                   float* __restrict__ out,
                                   int start, int n) {
    int i = start + blockIdx.x * blockDim.x + threadIdx.x;
    if (i < n) {
        float v = x[i];
        out[i] = v * v * 0.1f;
    }
}

extern "C" void kernel_launch(void* const* d_in, const int* in_sizes, int n_in,
                              void* d_out, int out_size, void* d_ws, size_t ws_size,
                              hipStream_t stream) {
    const float* x = (const float*)d_in[0];
    float* out = (float*)d_out;
    int n = out_size;

    int n4 = n / 4;
    if (n4 > 0) {
        const int block = 256;
        int grid = (n4 + block - 1) / block;
        poly_sq_scale_v4<<<grid, block, 0, stream>>>(
            (const vfloat4*)x, (vfloat4*)out, n4);
    }
    int tail_start = n4 * 4;
    int tail = n - tail_start;
    if (tail > 0) {
        poly_sq_scale_tail<<<1, 64, 0, stream>>>(x, out, tail_start, n);
    }
}